// Round 17
// baseline (108.833 us; speedup 1.0000x reference)
//
#include <hip/hip_runtime.h>

// LDDMM variational evolve: N-body Gaussian kernel sums, N=8192, D=3, fp32.
// dmom_i = (1/SIG2) * sum_j K_ij * <mom_i,mom_j> * (pos_i - pos_j)
// dpos_i = sum_j K_ij * mom_j
// K_ij = exp(-||xi-xj||^2/(2*SIG2)), SIG2=0.01 -> exp2(-72.1348*d2)
//
// Cell list: K < 4e-6 for d2 > 0.25; dropped-pair error ~1e-2 << thr 2.36.
// Ladder: R13 24.9; R15 24.4; R16 split-hist REGRESSED 33.5 (+2 dispatches
// = +9.1us -> per-dispatch ~4.5us dominates, not kernel bodies). R17:
// TWO dispatches. D1 = R15 countscan (1 block LDS hist+scan) + zero barrier
// words (every replay). D2 = scatter -> manual grid barrier -> main.
// Grid2 = 1024 blocks x 256 thr = 4 blocks/CU (16 waves/CU << 32 cap, no
// LDS, low VGPR) -> all co-resident; device-scope ticket barrier is sound.
// Main: wave handles 2 sorted points serially (R15 per-point logic).
// R7 NaN lesson: ci stays inside the exponent (arg <= 0 always).
// exp = __builtin_amdgcn_exp2f (plain exp2f -> OCML fixup; R2 measured).

#define NPTS  8192
#define NCXY  16
#define NCZ   32
#define NCELL (NCXY * NCXY * NCZ)   // 8192
#define ORIGIN    (-4.0f)
#define EDGE      0.5f
#define INV_EDGE  2.0f              // xy edge 0.5
#define INV_EDGEZ 4.0f              // z slab 0.25
#define RCUT2     0.25f
#define NB2   1024                  // dispatch-2 blocks (4/CU, co-resident)

#define A_DOT 144.269504088896f     // 2*50*log2(e)
#define A_R   (-72.134752044448f)   // -50*log2(e)
#define INV_SIG2 100.0f

#define EXP2(x) __builtin_amdgcn_exp2f(x)

__device__ __forceinline__ int clampi(int c, int hi) { return min(max(c, 0), hi); }

__device__ __forceinline__ int cell_of(float x, float y, float z) {
    const int cx = clampi((int)floorf((x - ORIGIN) * INV_EDGE),  NCXY - 1);
    const int cy = clampi((int)floorf((y - ORIGIN) * INV_EDGE),  NCXY - 1);
    const int cz = clampi((int)floorf((z - ORIGIN) * INV_EDGEZ), NCZ  - 1);
    return (cx * NCXY + cy) * NCZ + cz;
}

// ---------- dispatch 1: hist (LDS) + scan, one block; zero barrier words ----
__global__ __launch_bounds__(1024)
void k_countscan(const float* __restrict__ pos,
                 int* __restrict__ start, int* __restrict__ cur,
                 int* __restrict__ bar)
{
    __shared__ int cnt[NCELL];      // 32 KB
    __shared__ int wtot[16];
    __shared__ int wexcl[16];
    const int t = threadIdx.x;
    const int lane = t & 63;
    const int wid = t >> 6;

    if (t == 0) { bar[0] = 0; bar[1] = 0; }   // barrier slots, every replay

    #pragma unroll
    for (int k = 0; k < NCELL / 1024; ++k) cnt[t + k * 1024] = 0;
    __syncthreads();

    #pragma unroll
    for (int k = 0; k < NPTS / 1024; ++k) {
        const int i = t + k * 1024;
        atomicAdd(&cnt[cell_of(pos[3*i+0], pos[3*i+1], pos[3*i+2])], 1);
    }
    __syncthreads();

    // scan 8192 bins: thread t owns cells 8t..8t+7
    int pre[8];
    int s = 0;
    #pragma unroll
    for (int k = 0; k < 8; ++k) { pre[k] = s; s += cnt[8*t + k]; }
    int p = s;
    #pragma unroll
    for (int off = 1; off < 64; off <<= 1) {
        const int v = __shfl_up(p, off);
        if (lane >= off) p += v;
    }
    if (lane == 63) wtot[wid] = p;
    __syncthreads();
    if (t < 16) {
        const int w = wtot[t];
        int q = w;
        #pragma unroll
        for (int off = 1; off < 16; off <<= 1) {
            const int v = __shfl_up(q, off);
            if (t >= off) q += v;
        }
        wexcl[t] = q - w;
    }
    __syncthreads();
    const int base = wexcl[wid] + (p - s);
    #pragma unroll
    for (int k = 0; k < 8; ++k) {
        const int v = base + pre[k];
        start[8*t + k] = v;
        cur[8*t + k] = v;
    }
    if (t == 0) start[NCELL] = NPTS;
}

// ---------- dispatch 2: scatter -> grid barrier -> main ----------
__device__ __forceinline__ void gridbar(int* bar)
{
    __syncthreads();
    if (threadIdx.x == 0) {
        __threadfence();   // release prior writes to device scope
        const int old = __hip_atomic_fetch_add(&bar[0], 1, __ATOMIC_ACQ_REL,
                                               __HIP_MEMORY_SCOPE_AGENT);
        if (old == NB2 - 1) {
            __hip_atomic_store(&bar[1], 1, __ATOMIC_RELEASE,
                               __HIP_MEMORY_SCOPE_AGENT);
        } else {
            while (__hip_atomic_load(&bar[1], __ATOMIC_ACQUIRE,
                                     __HIP_MEMORY_SCOPE_AGENT) == 0) {}
        }
        __threadfence();   // acquire side
    }
    __syncthreads();
}

__global__ __launch_bounds__(256, 4)
void k_fused(const float* __restrict__ mom, const float* __restrict__ pos,
             int* __restrict__ cur, const int* __restrict__ start,
             float* __restrict__ pmP, float* __restrict__ pmM,
             int* __restrict__ inv, int* __restrict__ bar,
             float* __restrict__ out)
{
    const int tid = blockIdx.x * 256 + threadIdx.x;

    // ---- phase 1: scatter (blocks 0..31 carry the work) ----
    if (tid < NPTS) {
        const float x = pos[3*tid+0], y = pos[3*tid+1], z = pos[3*tid+2];
        const int dst = atomicAdd(&cur[cell_of(x, y, z)], 1);
        const float r2 = x*x + y*y + z*z;
        reinterpret_cast<float4*>(pmP)[dst] =
            make_float4(A_DOT*x, A_DOT*y, A_DOT*z, A_R*r2);
        reinterpret_cast<float4*>(pmM)[dst] =
            make_float4(mom[3*tid+0], mom[3*tid+1], mom[3*tid+2], 0.0f);
        inv[dst] = tid;
    }

    // ---- grid barrier ----
    gridbar(bar);

    // ---- phase 2: main; wave handles 2 sorted points serially ----
    const int w    = tid >> 6;          // 0..4095
    const int lane = tid & 63;
    const float4* __restrict__ pmPv = reinterpret_cast<const float4*>(pmP);
    const float4* __restrict__ pmMv = reinterpret_cast<const float4*>(pmM);

    #pragma unroll 1
    for (int half = 0; half < 2; ++half) {
        const int si = 2 * w + half;
        const int oi = inv[si];                               // wave-uniform
        const float xi = pos[3*oi+0], yi = pos[3*oi+1], zi = pos[3*oi+2];
        const float pxi = mom[3*oi+0], pyi = mom[3*oi+1], pzi = mom[3*oi+2];
        const float ci  = A_R * (xi*xi + yi*yi + zi*zi);

        const int cx = clampi((int)floorf((xi - ORIGIN) * INV_EDGE), NCXY - 1);
        const int cy = clampi((int)floorf((yi - ORIGIN) * INV_EDGE), NCXY - 1);

        // Lanes 0..8: fixed 3x3 columns; out-of-domain or xy-pruned -> empty.
        int st_l = 0, en_l = 0;
        if (lane < 9) {
            const int nx = cx + (lane / 3) - 1;
            const int ny = cy + (lane % 3) - 1;
            if (nx >= 0 && nx < NCXY && ny >= 0 && ny < NCXY) {
                const float X0 = ORIGIN + nx * EDGE;
                const float Y0 = ORIGIN + ny * EDGE;
                const float dx = fmaxf(fmaxf(X0 - xi, xi - (X0 + EDGE)), 0.0f);
                const float dy = fmaxf(fmaxf(Y0 - yi, yi - (Y0 + EDGE)), 0.0f);
                const float m2 = dx * dx + dy * dy;
                if (m2 <= RCUT2) {
                    const float zr = __builtin_sqrtf(RCUT2 - m2);
                    const int z0 = clampi((int)floorf((zi - zr - ORIGIN) * INV_EDGEZ), NCZ - 1);
                    const int z1 = clampi((int)floorf((zi + zr - ORIGIN) * INV_EDGEZ), NCZ - 1);
                    const int base = (nx * NCXY + ny) * NCZ;
                    st_l = start[base + z0];
                    en_l = start[base + z1 + 1];
                }
            }
        }

        float S = 0.f, SPx = 0.f, SPy = 0.f, SPz = 0.f;
        float apx = 0.f, apy = 0.f, apz = 0.f;

        #pragma unroll
        for (int p = 0; p < 9; ++p) {
            const int st = __shfl(st_l, p);   // constant lane -> readlane
            const int en = __shfl(en_l, p);
            for (int j = st + lane; j < en; j += 64) {
                const float4 P = pmPv[j];     // coalesced
                const float4 M = pmMv[j];
                // arg = ci + A_DOT*<xi,xj> + A_R*rj2 = -72.13*d2 <= 0
                float arg = __builtin_fmaf(zi, P.z, ci + P.w);
                arg = __builtin_fmaf(yi, P.y, arg);
                arg = __builtin_fmaf(xi, P.x, arg);
                const float K = EXP2(arg);
                const float C = __builtin_fmaf(pzi, M.z,
                                  __builtin_fmaf(pyi, M.y, pxi * M.x));
                const float s = K * C;
                S += s;
                SPx = __builtin_fmaf(s, P.x, SPx);
                SPy = __builtin_fmaf(s, P.y, SPy);
                SPz = __builtin_fmaf(s, P.z, SPz);
                apx = __builtin_fmaf(K, M.x, apx);
                apy = __builtin_fmaf(K, M.y, apy);
                apz = __builtin_fmaf(K, M.z, apz);
            }
        }

        // 64-lane butterfly reduce of the 7 accumulators.
        #pragma unroll
        for (int off = 1; off < 64; off <<= 1) {
            S   += __shfl_xor(S,   off);
            SPx += __shfl_xor(SPx, off);
            SPy += __shfl_xor(SPy, off);
            SPz += __shfl_xor(SPz, off);
            apx += __shfl_xor(apx, off);
            apy += __shfl_xor(apy, off);
            apz += __shfl_xor(apz, off);
        }

        if (lane == 0) {
            const float us = INV_SIG2 / A_DOT;
            out[3*oi+0] = INV_SIG2 * xi * S - us * SPx;
            out[3*oi+1] = INV_SIG2 * yi * S - us * SPy;
            out[3*oi+2] = INV_SIG2 * zi * S - us * SPz;
            out[3*NPTS + 3*oi+0] = apx;
            out[3*NPTS + 3*oi+1] = apy;
            out[3*NPTS + 3*oi+2] = apz;
        }
    }
}

extern "C" void kernel_launch(void* const* d_in, const int* in_sizes, int n_in,
                              void* d_out, int out_size, void* d_ws, size_t ws_size,
                              hipStream_t stream)
{
    const float* mom = (const float*)d_in[0];
    const float* pos = (const float*)d_in[1];
    float* out = (float*)d_out;

    // ws layout: pmP (4*NPTS f), pmM (4*NPTS f), inv (NPTS i),
    //            start (NCELL+1 i), cur (NCELL i), bar (2 i)  -> ~355 KB
    float* pmP  = (float*)d_ws;
    float* pmM  = pmP + (size_t)4 * NPTS;
    int* inv    = (int*)(pmM + (size_t)4 * NPTS);
    int* start  = inv + NPTS;
    int* cur    = start + NCELL + 1;
    int* bar    = cur + NCELL;

    k_countscan<<<1, 1024, 0, stream>>>(pos, start, cur, bar);
    k_fused<<<NB2, 256, 0, stream>>>(mom, pos, cur, start, pmP, pmM, inv, bar, out);
}

// Round 18
// 23.942 us; speedup vs baseline: 4.5456x; 4.5456x over previous
//
#include <hip/hip_runtime.h>

// LDDMM variational evolve: N-body Gaussian kernel sums, N=8192, D=3, fp32.
// dmom_i = (1/SIG2) * sum_j K_ij * <mom_i,mom_j> * (pos_i - pos_j)
// dpos_i = sum_j K_ij * mom_j
// K_ij = exp(-||xi-xj||^2/(2*SIG2)), SIG2=0.01 -> exp2(-72.1348*d2)
//
// Cell list: K < 4e-6 for d2 > 0.25; dropped-pair error ~1e-2 << thr 2.36.
// Ladder: R13 24.9; R15 24.4; R16 global-atomic hist REGRESSED (hot-cell
// same-address L2 atomic chains, NOT dispatch tax); R17 spin grid-barrier
// CATASTROPHIC 108 (spin atomics starve L2). R18: main's inner loop is
// quantized at sum(ceil(len_col/64)) ~ 9-13 iters/point (why R15's -25%
// pairs bought only -0.5us). FLATTEN the 9 z-clipped ranges into one
// virtual stream (T = sum len, ceil(T/64) ~ 3-8 iters); per-lane column
// select = 8-step cndmask cascade over wave-uniform (readlane/SGPR)
// prefix table. Prep = R15 unchanged (single-variable experiment).
// R7 NaN lesson: ci stays inside the exponent (arg <= 0 always).
// exp = __builtin_amdgcn_exp2f (plain exp2f -> OCML fixup; R2 measured).

#define NPTS  8192
#define NCXY  16
#define NCZ   32
#define NCELL (NCXY * NCXY * NCZ)   // 8192
#define ORIGIN    (-4.0f)
#define EDGE      0.5f
#define INV_EDGE  2.0f              // xy edge 0.5
#define INV_EDGEZ 4.0f              // z slab 0.25
#define RCUT2     0.25f

#define A_DOT 144.269504088896f     // 2*50*log2(e)
#define A_R   (-72.134752044448f)   // -50*log2(e)
#define INV_SIG2 100.0f

#define EXP2(x) __builtin_amdgcn_exp2f(x)

__device__ __forceinline__ int clampi(int c, int hi) { return min(max(c, 0), hi); }

__device__ __forceinline__ int cell_of(float x, float y, float z) {
    const int cx = clampi((int)floorf((x - ORIGIN) * INV_EDGE),  NCXY - 1);
    const int cy = clampi((int)floorf((y - ORIGIN) * INV_EDGE),  NCXY - 1);
    const int cz = clampi((int)floorf((z - ORIGIN) * INV_EDGEZ), NCZ  - 1);
    return (cx * NCXY + cy) * NCZ + cz;
}

// ---------------- prep 1: count (LDS hist) + scan, one block ----------------
__global__ __launch_bounds__(1024)
void k_countscan(const float* __restrict__ pos,
                 int* __restrict__ start, int* __restrict__ cur)
{
    __shared__ int cnt[NCELL];      // 32 KB
    __shared__ int wtot[16];
    __shared__ int wexcl[16];
    const int t = threadIdx.x;
    const int lane = t & 63;
    const int wid = t >> 6;

    #pragma unroll
    for (int k = 0; k < NCELL / 1024; ++k) cnt[t + k * 1024] = 0;
    __syncthreads();

    #pragma unroll
    for (int k = 0; k < NPTS / 1024; ++k) {
        const int i = t + k * 1024;
        atomicAdd(&cnt[cell_of(pos[3*i+0], pos[3*i+1], pos[3*i+2])], 1);
    }
    __syncthreads();

    // scan 8192 bins: thread t owns cells 8t..8t+7
    int pre[8];
    int s = 0;
    #pragma unroll
    for (int k = 0; k < 8; ++k) { pre[k] = s; s += cnt[8*t + k]; }
    int p = s;
    #pragma unroll
    for (int off = 1; off < 64; off <<= 1) {
        const int v = __shfl_up(p, off);
        if (lane >= off) p += v;
    }
    if (lane == 63) wtot[wid] = p;
    __syncthreads();
    if (t < 16) {
        const int w = wtot[t];
        int q = w;
        #pragma unroll
        for (int off = 1; off < 16; off <<= 1) {
            const int v = __shfl_up(q, off);
            if (t >= off) q += v;
        }
        wexcl[t] = q - w;
    }
    __syncthreads();
    const int base = wexcl[wid] + (p - s);
    #pragma unroll
    for (int k = 0; k < 8; ++k) {
        const int v = base + pre[k];
        start[8*t + k] = v;
        cur[8*t + k] = v;
    }
    if (t == 0) start[NCELL] = NPTS;
}

// ---------------- prep 2: scatter (parallel, atomic cursor ranks) ----------------
__global__ __launch_bounds__(256)
void k_scatter(const float* __restrict__ mom, const float* __restrict__ pos,
               int* __restrict__ cur,
               float* __restrict__ pmP, float* __restrict__ pmM,
               int* __restrict__ inv)
{
    const int i = blockIdx.x * 256 + threadIdx.x;
    const float x = pos[3*i+0], y = pos[3*i+1], z = pos[3*i+2];
    const int dst = atomicAdd(&cur[cell_of(x, y, z)], 1);
    const float r2 = x*x + y*y + z*z;
    reinterpret_cast<float4*>(pmP)[dst] = make_float4(A_DOT*x, A_DOT*y, A_DOT*z, A_R*r2);
    reinterpret_cast<float4*>(pmM)[dst] = make_float4(mom[3*i+0], mom[3*i+1], mom[3*i+2], 0.0f);
    inv[dst] = i;
}

// ------- main: one wave per point, FLATTENED 9-column virtual j-stream -------
__global__ __launch_bounds__(256)
void k_main(const float* __restrict__ mom, const float* __restrict__ pos,
            const float* __restrict__ pmP, const float* __restrict__ pmM,
            const int* __restrict__ inv, const int* __restrict__ start,
            float* __restrict__ out)
{
    const int wid  = (blockIdx.x * 256 + threadIdx.x) >> 6;   // 0..8191
    const int lane = threadIdx.x & 63;

    const int oi = inv[wid];                                  // wave-uniform
    const float xi = pos[3*oi+0], yi = pos[3*oi+1], zi = pos[3*oi+2];
    const float pxi = mom[3*oi+0], pyi = mom[3*oi+1], pzi = mom[3*oi+2];
    const float ci  = A_R * (xi*xi + yi*yi + zi*zi);

    const int cx = clampi((int)floorf((xi - ORIGIN) * INV_EDGE), NCXY - 1);
    const int cy = clampi((int)floorf((yi - ORIGIN) * INV_EDGE), NCXY - 1);

    // Lanes 0..8: fixed 3x3 columns, z-clipped range (st,len); pruned -> len 0.
    int st_l = 0, len_l = 0;
    if (lane < 9) {
        const int nx = cx + (lane / 3) - 1;
        const int ny = cy + (lane % 3) - 1;
        if (nx >= 0 && nx < NCXY && ny >= 0 && ny < NCXY) {
            const float X0 = ORIGIN + nx * EDGE;
            const float Y0 = ORIGIN + ny * EDGE;
            const float dx = fmaxf(fmaxf(X0 - xi, xi - (X0 + EDGE)), 0.0f);
            const float dy = fmaxf(fmaxf(Y0 - yi, yi - (Y0 + EDGE)), 0.0f);
            const float m2 = dx * dx + dy * dy;
            if (m2 <= RCUT2) {
                const float zr = __builtin_sqrtf(RCUT2 - m2);
                const int z0 = clampi((int)floorf((zi - zr - ORIGIN) * INV_EDGEZ), NCZ - 1);
                const int z1 = clampi((int)floorf((zi + zr - ORIGIN) * INV_EDGEZ), NCZ - 1);
                const int base = (nx * NCXY + ny) * NCZ;
                st_l  = start[base + z0];
                len_l = start[base + z1 + 1] - st_l;
            }
        }
    }

    // Inclusive prefix of len over lanes 0..8 (sources stay within 0..8).
    int pref = len_l;
    #pragma unroll
    for (int off = 1; off < 16; off <<= 1) {
        const int v = __shfl_up(pref, off);
        if (lane >= off) pref += v;
    }
    const int T = __shfl(pref, 8);    // total virtual stream length

    // Wave-uniform (SGPR) tables: p0[q] = exclusive prefix, ofs[q] = st - p0.
    int p0[9], ofs[9];
    #pragma unroll
    for (int q = 0; q < 9; ++q) {
        const int pr = __shfl(pref, q);
        const int ln = __shfl(len_l, q);
        const int st = __shfl(st_l, q);
        p0[q]  = pr - ln;
        ofs[q] = st - (pr - ln);
    }

    float S = 0.f, SPx = 0.f, SPy = 0.f, SPz = 0.f;
    float apx = 0.f, apy = 0.f, apz = 0.f;

    const float4* __restrict__ pmPv = reinterpret_cast<const float4*>(pmP);
    const float4* __restrict__ pmMv = reinterpret_cast<const float4*>(pmM);

    for (int f0 = 0; f0 < T; f0 += 64) {
        const int f = f0 + lane;
        // column select: largest q with p0[q] <= f (empty cols never win)
        int off_sel = ofs[0];
        #pragma unroll
        for (int q = 1; q < 9; ++q)
            off_sel = (f >= p0[q]) ? ofs[q] : off_sel;
        if (f < T) {
            const int j = f + off_sel;
            const float4 P = pmPv[j];     // mostly coalesced (segmented)
            const float4 M = pmMv[j];
            // arg = ci + A_DOT*<xi,xj> + A_R*rj2 = -72.13*d2 <= 0 (no overflow)
            float arg = __builtin_fmaf(zi, P.z, ci + P.w);
            arg = __builtin_fmaf(yi, P.y, arg);
            arg = __builtin_fmaf(xi, P.x, arg);
            const float K = EXP2(arg);
            const float C = __builtin_fmaf(pzi, M.z,
                              __builtin_fmaf(pyi, M.y, pxi * M.x));
            const float s = K * C;
            S += s;
            SPx = __builtin_fmaf(s, P.x, SPx);
            SPy = __builtin_fmaf(s, P.y, SPy);
            SPz = __builtin_fmaf(s, P.z, SPz);
            apx = __builtin_fmaf(K, M.x, apx);
            apy = __builtin_fmaf(K, M.y, apy);
            apz = __builtin_fmaf(K, M.z, apz);
        }
    }

    // 64-lane butterfly reduce of the 7 accumulators.
    #pragma unroll
    for (int off = 1; off < 64; off <<= 1) {
        S   += __shfl_xor(S,   off);
        SPx += __shfl_xor(SPx, off);
        SPy += __shfl_xor(SPy, off);
        SPz += __shfl_xor(SPz, off);
        apx += __shfl_xor(apx, off);
        apy += __shfl_xor(apy, off);
        apz += __shfl_xor(apz, off);
    }

    if (lane == 0) {
        const float us = INV_SIG2 / A_DOT;
        out[3*oi+0] = INV_SIG2 * xi * S - us * SPx;
        out[3*oi+1] = INV_SIG2 * yi * S - us * SPy;
        out[3*oi+2] = INV_SIG2 * zi * S - us * SPz;
        out[3*NPTS + 3*oi+0] = apx;
        out[3*NPTS + 3*oi+1] = apy;
        out[3*NPTS + 3*oi+2] = apz;
    }
}

extern "C" void kernel_launch(void* const* d_in, const int* in_sizes, int n_in,
                              void* d_out, int out_size, void* d_ws, size_t ws_size,
                              hipStream_t stream)
{
    const float* mom = (const float*)d_in[0];
    const float* pos = (const float*)d_in[1];
    float* out = (float*)d_out;

    // ws layout: pmP (4*NPTS f), pmM (4*NPTS f), inv (NPTS i),
    //            start (NCELL+1 i), cur (NCELL i)  -> ~355 KB
    float* pmP  = (float*)d_ws;
    float* pmM  = pmP + (size_t)4 * NPTS;
    int* inv    = (int*)(pmM + (size_t)4 * NPTS);
    int* start  = inv + NPTS;
    int* cur    = start + NCELL + 1;

    k_countscan<<<1, 1024, 0, stream>>>(pos, start, cur);
    k_scatter<<<NPTS / 256, 256, 0, stream>>>(mom, pos, cur, pmP, pmM, inv);
    k_main<<<(NPTS * 64) / 256, 256, 0, stream>>>(mom, pos, pmP, pmM, inv, start, out);
}